// Round 2
// baseline (997.478 us; speedup 1.0000x reference)
//
#include <hip/hip_runtime.h>
#include <hip/hip_bf16.h>
#include <math.h>

#define B_ 16
#define C_ 2048
#define HW_ 4096
#define NPIX_ 65536
#define PD_ 128
#define AD_ 64
#define S_ 64
#define BN_EPS_ 1e-5f
#define TEMP_ 0.1f
#define BTEMP_ 0.07f
#define THR_ 0.7f
#define LW_ 0.1f
#define NKC_ 64   // 2048 / 32

typedef __attribute__((ext_vector_type(8))) short short8;
typedef __attribute__((ext_vector_type(4))) float floatx4;

__device__ __forceinline__ unsigned short f2bf(float x) {
    unsigned int u = __float_as_uint(x);
    u += 0x7fffu + ((u >> 16) & 1u);   // round-to-nearest-even
    return (unsigned short)(u >> 16);
}

// ---------------- prep (blocks 0..127) + find (blocks 128..143), fused ----------------
// prep: zero stats/counter/out, transpose W2, pack W1 into bf16 MFMA B-fragment order.
// Bpk unit u = ((kc*4 + q)*128 + c): 8 bf16 = W1[c][kc*32+q*8 .. +7]  (16B per unit)
// find: first 64 valid pixels per image (row-major order).
__global__ __launch_bounds__(256) void prep_kernel(const float* __restrict__ W1,
                                                   const float* __restrict__ W2,
                                                   const int* __restrict__ labels,
                                                   float* __restrict__ W2t,
                                                   uint4* __restrict__ Bpk,
                                                   float* __restrict__ hsum,
                                                   float* __restrict__ ssq,
                                                   float* __restrict__ out,
                                                   unsigned int* __restrict__ counter,
                                                   int* __restrict__ idx) {
    __shared__ int cnt[256];
    __shared__ int pref[257];
    int blk = blockIdx.x, t = threadIdx.x;
    if (blk < 128) {
        int g = blk * 256 + t;
        if (blk == 0) {
            if (t < PD_) { hsum[t] = 0.0f; ssq[t] = 0.0f; }
            if (t == 0) { out[0] = 0.0f; *counter = 0u; }
        }
        if (g < PD_ * PD_) { int k = g >> 7, c = g & 127; W2t[g] = W2[c * PD_ + k]; }
        // g < 32768 always here
        {
            int kc = g >> 9, q = (g >> 7) & 3, c = g & 127;
            const float* src = W1 + (size_t)c * C_ + kc * 32 + q * 8;
            unsigned int w[4];
#pragma unroll
            for (int h = 0; h < 4; h++) {
                unsigned int lo = f2bf(src[2 * h]);
                unsigned int hi = f2bf(src[2 * h + 1]);
                w[h] = lo | (hi << 16);
            }
            Bpk[g] = make_uint4(w[0], w[1], w[2], w[3]);
        }
    } else {
        int b = blk - 128;
        const int* lb = labels + b * HW_;
        int base = t * 16, c0 = 0;
        for (int i = 0; i < 16; i++) c0 += (lb[base + i] == 1);
        cnt[t] = c0;
        __syncthreads();
        if (t == 0) {
            int s = 0;
            for (int i = 0; i < 256; i++) { pref[i] = s; s += cnt[i]; }
            pref[256] = s;
        }
        __syncthreads();
        int r = pref[t];
        for (int i = 0; i < 16; i++) {
            if (lb[base + i] == 1) {
                if (r < S_) idx[b * S_ + r] = base + i;
                r++;
            }
        }
        if (t == 0) {
            for (int k = pref[256]; k < S_; k++) idx[b * S_ + k] = 0;  // fill_value=0
        }
    }
}

// ---------------- fused BN stats + last-block finalize ----------------
// hsum[c] = sum_p (W1.x_p)[c], ssq[c] = sum_p (W1.x_p)[c]^2, via bf16 MFMA.
// grid: 1024 blocks = 16 images x 64 pixel-tiles (64 px). 4 waves, each wave owns 16 px.
// Last arriving block computes mean/invstd (b1 cancels in BN exactly).
__global__ __launch_bounds__(256, 4) void fused_stats_kernel(const float* __restrict__ feats,
                                                             const short8* __restrict__ Bpk,
                                                             float* __restrict__ hsum,
                                                             float* __restrict__ ssq,
                                                             float* __restrict__ mean,
                                                             float* __restrict__ invstd,
                                                             unsigned int* __restrict__ counter) {
    __shared__ float redS[4][PD_];
    __shared__ float redQ[4][PD_];
    __shared__ int lastflag;

    int t = threadIdx.x;
    int tile = blockIdx.x;
    int b = tile >> 6;
    int hw0 = (tile & 63) << 6;
    int wave = t >> 6, lane = t & 63;
    int qd = lane >> 4, ln16 = lane & 15;

    const float* pk = feats + (size_t)b * C_ * HW_ + (hw0 + wave * 16 + ln16)
                    + (size_t)qd * 8 * HW_;
    const short8* bp = Bpk + qd * 128 + ln16;

    floatx4 acc[8];
#pragma unroll
    for (int nt = 0; nt < 8; nt++) acc[nt] = (floatx4)0.0f;

#pragma unroll 2
    for (int kc = 0; kc < NKC_; kc++) {
        float av[8];
#pragma unroll
        for (int j = 0; j < 8; j++) av[j] = pk[(size_t)j * HW_];

        short8 afrag;
#pragma unroll
        for (int j = 0; j < 8; j++) afrag[j] = (short)f2bf(av[j]);

#pragma unroll
        for (int nt = 0; nt < 8; nt++) {
            short8 bfrag = bp[nt * 16];
            acc[nt] = __builtin_amdgcn_mfma_f32_16x16x32_bf16(afrag, bfrag, acc[nt], 0, 0, 0);
        }
        pk += (size_t)32 * HW_;
        bp += 512;
    }

    // epilogue: acc[nt][r] = h[pixel = qd*4+r][ch = nt*16+ln16]
#pragma unroll
    for (int nt = 0; nt < 8; nt++) {
        float sq = 0.0f, sm = 0.0f;
#pragma unroll
        for (int r = 0; r < 4; r++) {
            float v = acc[nt][r];
            sq = fmaf(v, v, sq);
            sm += v;
        }
        sq += __shfl_xor(sq, 16, 64);
        sq += __shfl_xor(sq, 32, 64);
        sm += __shfl_xor(sm, 16, 64);
        sm += __shfl_xor(sm, 32, 64);
        if (qd == 0) {
            redQ[wave][nt * 16 + ln16] = sq;
            redS[wave][nt * 16 + ln16] = sm;
        }
    }
    __syncthreads();
    if (t < PD_) {
        atomicAdd(&ssq[t],  redQ[0][t] + redQ[1][t] + redQ[2][t] + redQ[3][t]);
        atomicAdd(&hsum[t], redS[0][t] + redS[1][t] + redS[2][t] + redS[3][t]);
    }
    __threadfence();       // this thread's adds visible device-wide
    __syncthreads();       // whole block's adds done before the ticket bump
    if (t == 0) {
        unsigned int v = __hip_atomic_fetch_add(counter, 1u, __ATOMIC_ACQ_REL,
                                                __HIP_MEMORY_SCOPE_AGENT);
        lastflag = (v == 1023u);
    }
    __syncthreads();
    if (lastflag && t < PD_) {
        float hs = __hip_atomic_load(&hsum[t], __ATOMIC_RELAXED, __HIP_MEMORY_SCOPE_AGENT);
        float sq = __hip_atomic_load(&ssq[t],  __ATOMIC_RELAXED, __HIP_MEMORY_SCOPE_AGENT);
        float m0 = hs * (1.0f / NPIX_);
        float var = sq * (1.0f / NPIX_) - m0 * m0;
        mean[t] = m0;
        invstd[t] = rsqrtf(var + BN_EPS_);
    }
}

// ---------------- per-sample forward (fp32 exact): 4 samples per block ----------------
__global__ __launch_bounds__(256) void sample_kernel(
        const float* __restrict__ feats, const float* __restrict__ W1,
        const float* __restrict__ Wa1, const float* __restrict__ mean,
        const float* __restrict__ invstd, const float* __restrict__ gamma,
        const float* __restrict__ beta, const float* __restrict__ W2t,
        const float* __restrict__ b2, const float* __restrict__ Wa2,
        const float* __restrict__ ba1, const float* __restrict__ ba2,
        const int* __restrict__ idx, float* __restrict__ projs, float* __restrict__ tw) {
    __shared__ float x[4][C_];         // 32 KB
    __shared__ float part[4][2][PD_];  // 4 KB
    __shared__ float aprt[4][2][AD_];  // 2 KB
    __shared__ float rh[4][PD_];       // 2 KB
    __shared__ float av[4][AD_];       // 1 KB

    int blk = blockIdx.x;
    int s0 = blk * 4;
    int b = s0 >> 6;                   // 4 samples always within one image (64 per image)
    int t = threadIdx.x;
    const float* fb = feats + (size_t)b * C_ * HW_;

    // gather: thread serves a fixed px = t&3 (no runtime-indexed array -> no scratch)
    {
        int px = t & 3;
        int pixv = idx[s0 + px];
        for (int c = (t >> 2); c < C_; c += 64)
            x[px][c] = fb[(size_t)c * HW_ + pixv];
    }
    __syncthreads();

    // phase1a: proj first layer. o = t&127, half = t>>7, 1024 k each, 4 px
    {
        int o = t & 127, half = t >> 7;
        const float* wr = W1 + (size_t)o * C_ + half * 1024;
        float pa[4], pb[4];
#pragma unroll
        for (int px = 0; px < 4; px++) { pa[px] = 0.0f; pb[px] = 0.0f; }
        for (int k = 0; k < 1024; k += 4) {
            float4 w4 = *(const float4*)(wr + k);
#pragma unroll
            for (int px = 0; px < 4; px++) {
                float4 x4 = *(const float4*)(&x[px][half * 1024 + k]);
                pa[px] = fmaf(w4.x, x4.x, pa[px]);
                pb[px] = fmaf(w4.y, x4.y, pb[px]);
                pa[px] = fmaf(w4.z, x4.z, pa[px]);
                pb[px] = fmaf(w4.w, x4.w, pb[px]);
            }
        }
#pragma unroll
        for (int px = 0; px < 4; px++) part[px][half][o] = pa[px] + pb[px];
    }
    // phase1b: attention first layer. threads 0..127: j = t&63, half = t>>6
    if (t < 128) {
        int j = t & 63, half = t >> 6;
        const float* wr = Wa1 + (size_t)j * C_ + half * 1024;
        float pa[4], pb[4];
#pragma unroll
        for (int px = 0; px < 4; px++) { pa[px] = 0.0f; pb[px] = 0.0f; }
        for (int k = 0; k < 1024; k += 4) {
            float4 w4 = *(const float4*)(wr + k);
#pragma unroll
            for (int px = 0; px < 4; px++) {
                float4 x4 = *(const float4*)(&x[px][half * 1024 + k]);
                pa[px] = fmaf(w4.x, x4.x, pa[px]);
                pb[px] = fmaf(w4.y, x4.y, pb[px]);
                pa[px] = fmaf(w4.z, x4.z, pa[px]);
                pb[px] = fmaf(w4.w, x4.w, pb[px]);
            }
        }
#pragma unroll
        for (int px = 0; px < 4; px++) aprt[px][half][j] = pa[px] + pb[px];
    }
    __syncthreads();

    // phase2: BN (b1 cancels) + ReLU; attention bias + ReLU
    if (t < PD_) {
        float mn = mean[t], is = invstd[t], g = gamma[t], be = beta[t];
#pragma unroll
        for (int px = 0; px < 4; px++) {
            float h = part[px][0][t] + part[px][1][t];
            float r = (h - mn) * is * g + be;
            rh[px][t] = r > 0.0f ? r : 0.0f;
        }
    } else if (t < PD_ + AD_) {
        int j = t - PD_;
        float bj = ba1[j];
#pragma unroll
        for (int px = 0; px < 4; px++) {
            float a = aprt[px][0][j] + aprt[px][1][j] + bj;
            av[px][j] = a > 0.0f ? a : 0.0f;
        }
    }
    __syncthreads();

    // phase3: W2 (shared weight load across 4 samples) + attention scalar
    if (t < PD_) {
        float p[4];
#pragma unroll
        for (int px = 0; px < 4; px++) p[px] = b2[t];
        for (int j = 0; j < PD_; j++) {
            float w = W2t[j * PD_ + t];
#pragma unroll
            for (int px = 0; px < 4; px++) p[px] = fmaf(w, rh[px][j], p[px]);
        }
#pragma unroll
        for (int px = 0; px < 4; px++) projs[(s0 + px) * PD_ + t] = p[px];
    } else if (t < PD_ + 4) {
        int px = t - PD_;
        float a2 = ba2[0];
        for (int j = 0; j < AD_; j++) a2 = fmaf(Wa2[j], av[px][j], a2);
        tw[s0 + px] = 1.0f / (1.0f + expf(-a2));
    }
}

// ---------------- per-image contrastive loss ----------------
__global__ __launch_bounds__(256) void loss_kernel(const float* __restrict__ projs,
                                                   const float* __restrict__ tw,
                                                   float* __restrict__ out) {
    __shared__ float f[S_][PD_ + 1];   // padded
    __shared__ float w[S_], inv[S_], rowsum[S_];
    __shared__ float sims[S_ * S_];    // 16 KB
    __shared__ float red[4];
    int b = blockIdx.x, t = threadIdx.x;
    for (int e = t; e < S_ * PD_; e += 256) {
        int i = e >> 7, c = e & 127;
        f[i][c] = projs[(b * S_ + i) * PD_ + c];
    }
    if (t < S_) w[t] = tw[b * S_ + t];
    __syncthreads();
    if (t < S_) {
        float s2 = 0.0f;
        for (int c = 0; c < PD_; c++) { float v = f[t][c]; s2 = fmaf(v, v, s2); }
        float n = sqrtf(s2);
        n = n < 1e-12f ? 1e-12f : n;
        inv[t] = 1.0f / n;
    }
    __syncthreads();
    for (int e = t; e < S_ * PD_; e += 256) {
        int i = e >> 7, c = e & 127;
        f[i][c] *= inv[i];
    }
    __syncthreads();
#pragma unroll
    for (int r = 0; r < 16; r++) {
        int e = t + 256 * r;
        int i = e >> 6, j = e & 63;
        float d = 0.0f;
        for (int c = 0; c < PD_; c++) d = fmaf(f[i][c], f[j][c], d);
        sims[e] = d * (1.0f / TEMP_);
    }
    __syncthreads();
    if (t < S_) {
        float rs = 0.0f;
        for (int jj = 0; jj < S_; jj++) {
            int j = (jj + t) & 63;
            rs += expf(sims[t * S_ + j]);
        }
        rowsum[t] = rs;
    }
    __syncthreads();
    float acc = 0.0f;
#pragma unroll
    for (int r = 0; r < 16; r++) {
        int e = t + 256 * r;
        int i = e >> 6, j = e & 63;
        float sv = sims[e];
        if (sv > THR_ && i != j) {
            float lp = logf(expf(sv) / rowsum[i] + 1e-10f);
            acc += w[i] * w[j] * lp;
        }
    }
    for (int o = 32; o > 0; o >>= 1) acc += __shfl_down(acc, o, 64);
    if ((t & 63) == 0) red[t >> 6] = acc;
    __syncthreads();
    if (t == 0) {
        float total = red[0] + red[1] + red[2] + red[3];
        float twsum = 0.0f;
        for (int i = 0; i < S_; i++) twsum += w[i];
        float loss = -(TEMP_ / BTEMP_) * total / twsum;
        atomicAdd(out, loss * (LW_ / B_));
    }
}

extern "C" void kernel_launch(void* const* d_in, const int* in_sizes, int n_in,
                              void* d_out, int out_size, void* d_ws, size_t ws_size,
                              hipStream_t stream) {
    const float* feats = (const float*)d_in[0];
    const int*   labels = (const int*)d_in[1];
    const float* W1 = (const float*)d_in[2];
    const float* b1 = (const float*)d_in[3];   (void)b1;  // cancels in BN exactly
    const float* gamma = (const float*)d_in[4];
    const float* beta = (const float*)d_in[5];
    const float* W2 = (const float*)d_in[6];
    const float* b2 = (const float*)d_in[7];
    const float* Wa1 = (const float*)d_in[8];
    const float* ba1 = (const float*)d_in[9];
    const float* Wa2 = (const float*)d_in[10];
    const float* ba2 = (const float*)d_in[11];
    float* out = (float*)d_out;

    // workspace layout — Bpk first for 16B alignment
    uint4* Bpk   = (uint4*)d_ws;                    // 32768 uint4 = 512 KB
    float* W2t   = (float*)(Bpk + NKC_ * 4 * PD_);  // 16384
    float* hsum  = W2t + PD_ * PD_;                 // 128
    float* ssq   = hsum + PD_;                      // 128
    float* mean  = ssq + PD_;                       // 128
    float* invstd= mean + PD_;                      // 128
    float* tw    = invstd + PD_;                    // 1024
    int*   idx   = (int*)(tw + B_ * S_);            // 1024 ints
    unsigned int* counter = (unsigned int*)(idx + B_ * S_);  // 1 (+3 pad)
    float* projs = (float*)(counter + 4);           // 131072

    prep_kernel<<<144, 256, 0, stream>>>(W1, W2, labels, W2t, Bpk, hsum, ssq, out,
                                         counter, idx);
    fused_stats_kernel<<<1024, 256, 0, stream>>>(feats, (const short8*)Bpk, hsum, ssq,
                                                 mean, invstd, counter);
    sample_kernel<<<256, 256, 0, stream>>>(feats, W1, Wa1, mean, invstd, gamma, beta,
                                           W2t, b2, Wa2, ba1, ba2, idx, projs, tw);
    loss_kernel<<<B_, 256, 0, stream>>>(projs, tw, out);
}

// Round 3
// 895.351 us; speedup vs baseline: 1.1141x; 1.1141x over previous
//
#include <hip/hip_runtime.h>
#include <hip/hip_bf16.h>
#include <math.h>

#define B_ 16
#define C_ 2048
#define HW_ 4096
#define NPIX_ 65536
#define PD_ 128
#define AD_ 64
#define S_ 64
#define BN_EPS_ 1e-5f
#define TEMP_ 0.1f
#define BTEMP_ 0.07f
#define THR_ 0.7f
#define LW_ 0.1f
#define NKC_ 64   // 2048 / 32

typedef __attribute__((ext_vector_type(8))) short short8;
typedef __attribute__((ext_vector_type(4))) float floatx4;

__device__ __forceinline__ unsigned short f2bf(float x) {
    unsigned int u = __float_as_uint(x);
    u += 0x7fffu + ((u >> 16) & 1u);   // round-to-nearest-even
    return (unsigned short)(u >> 16);
}

// ---------------- prep (blocks 0..127) + find (blocks 128..143), fused ----------------
// prep: zero stats/out, transpose W2, pack W1 into bf16 MFMA B-fragment order.
// Bpk unit u = ((kc*4 + q)*128 + c): 8 bf16 = W1[c][kc*32+q*8 .. +7]  (16B per unit)
// find: first 64 valid pixels per image (row-major order).
__global__ __launch_bounds__(256) void prep_kernel(const float* __restrict__ W1,
                                                   const float* __restrict__ W2,
                                                   const int* __restrict__ labels,
                                                   float* __restrict__ W2t,
                                                   uint4* __restrict__ Bpk,
                                                   float* __restrict__ hsum,
                                                   float* __restrict__ ssq,
                                                   float* __restrict__ out,
                                                   int* __restrict__ idx) {
    __shared__ int cnt[256];
    __shared__ int pref[257];
    int blk = blockIdx.x, t = threadIdx.x;
    if (blk < 128) {
        int g = blk * 256 + t;
        if (blk == 0) {
            if (t < PD_) { hsum[t] = 0.0f; ssq[t] = 0.0f; }
            if (t == 0) out[0] = 0.0f;
        }
        if (g < PD_ * PD_) { int k = g >> 7, c = g & 127; W2t[g] = W2[c * PD_ + k]; }
        // g < 32768 always here
        {
            int kc = g >> 9, q = (g >> 7) & 3, c = g & 127;
            const float* src = W1 + (size_t)c * C_ + kc * 32 + q * 8;
            unsigned int w[4];
#pragma unroll
            for (int h = 0; h < 4; h++) {
                unsigned int lo = f2bf(src[2 * h]);
                unsigned int hi = f2bf(src[2 * h + 1]);
                w[h] = lo | (hi << 16);
            }
            Bpk[g] = make_uint4(w[0], w[1], w[2], w[3]);
        }
    } else {
        int b = blk - 128;
        const int* lb = labels + b * HW_;
        int base = t * 16, c0 = 0;
        for (int i = 0; i < 16; i++) c0 += (lb[base + i] == 1);
        cnt[t] = c0;
        __syncthreads();
        if (t == 0) {
            int s = 0;
            for (int i = 0; i < 256; i++) { pref[i] = s; s += cnt[i]; }
            pref[256] = s;
        }
        __syncthreads();
        int r = pref[t];
        for (int i = 0; i < 16; i++) {
            if (lb[base + i] == 1) {
                if (r < S_) idx[b * S_ + r] = base + i;
                r++;
            }
        }
        if (t == 0) {
            for (int k = pref[256]; k < S_; k++) idx[b * S_ + k] = 0;  // fill_value=0
        }
    }
}

// ---------------- mega: sample phase1 (blocks 0..255) + BN stats (blocks 256..1279) ----
// sample path: gather 4 pixels' features, compute fp32 W1.x (raw partial h) and
//              relu(Wa1.x + ba1) into workspace. Independent of BN stats.
// stats path:  hsum[c]=sum_p (W1.x_p)[c], ssq[c]=sum_p (..)^2 via bf16 MFMA, atomicAdd.
// Sample blocks first: latency-bound gather overlaps the BW-bound stats stream.
#define SMEM_F_ (4 * C_ + 4 * 2 * PD_ + 4 * 2 * AD_)   // 9728 floats = 38.9 KB
__global__ __launch_bounds__(256, 4) void mega_kernel(const float* __restrict__ feats,
                                                      const short8* __restrict__ Bpk,
                                                      const float* __restrict__ W1,
                                                      const float* __restrict__ Wa1,
                                                      const float* __restrict__ ba1,
                                                      const int* __restrict__ idx,
                                                      float* __restrict__ hsum,
                                                      float* __restrict__ ssq,
                                                      float* __restrict__ hpart,
                                                      float* __restrict__ avw) {
    __shared__ float smem[SMEM_F_];
    int blk = blockIdx.x, t = threadIdx.x;

    if (blk < 256) {
        // ---------------- sample phase1 ----------------
        float (*x)[C_] = (float (*)[C_])smem;                              // 4x2048
        float (*part)[2][PD_] = (float (*)[2][PD_])(smem + 4 * C_);        // 4x2x128
        float (*aprt)[2][AD_] = (float (*)[2][AD_])(smem + 4 * C_ + 4 * 2 * PD_);
        int s0 = blk * 4;
        int b = s0 >> 6;               // 4 samples always within one image
        const float* fb = feats + (size_t)b * C_ * HW_;
        {
            int px = t & 3;
            int pixv = idx[s0 + px];
            for (int c = (t >> 2); c < C_; c += 64)
                x[px][c] = fb[(size_t)c * HW_ + pixv];
        }
        __syncthreads();
        // phase1a: proj first layer. o = t&127, half = t>>7, 1024 k each, 4 px
        {
            int o = t & 127, half = t >> 7;
            const float* wr = W1 + (size_t)o * C_ + half * 1024;
            float pa[4], pb[4];
#pragma unroll
            for (int px = 0; px < 4; px++) { pa[px] = 0.0f; pb[px] = 0.0f; }
            for (int k = 0; k < 1024; k += 4) {
                float4 w4 = *(const float4*)(wr + k);
#pragma unroll
                for (int px = 0; px < 4; px++) {
                    float4 x4 = *(const float4*)(&x[px][half * 1024 + k]);
                    pa[px] = fmaf(w4.x, x4.x, pa[px]);
                    pb[px] = fmaf(w4.y, x4.y, pb[px]);
                    pa[px] = fmaf(w4.z, x4.z, pa[px]);
                    pb[px] = fmaf(w4.w, x4.w, pb[px]);
                }
            }
#pragma unroll
            for (int px = 0; px < 4; px++) part[px][half][o] = pa[px] + pb[px];
        }
        // phase1b: attention first layer. threads 0..127: j = t&63, half = t>>6
        if (t < 128) {
            int j = t & 63, half = t >> 6;
            const float* wr = Wa1 + (size_t)j * C_ + half * 1024;
            float pa[4], pb[4];
#pragma unroll
            for (int px = 0; px < 4; px++) { pa[px] = 0.0f; pb[px] = 0.0f; }
            for (int k = 0; k < 1024; k += 4) {
                float4 w4 = *(const float4*)(wr + k);
#pragma unroll
                for (int px = 0; px < 4; px++) {
                    float4 x4 = *(const float4*)(&x[px][half * 1024 + k]);
                    pa[px] = fmaf(w4.x, x4.x, pa[px]);
                    pb[px] = fmaf(w4.y, x4.y, pb[px]);
                    pa[px] = fmaf(w4.z, x4.z, pa[px]);
                    pb[px] = fmaf(w4.w, x4.w, pb[px]);
                }
            }
#pragma unroll
            for (int px = 0; px < 4; px++) aprt[px][half][j] = pa[px] + pb[px];
        }
        __syncthreads();
        if (t < PD_) {
#pragma unroll
            for (int px = 0; px < 4; px++)
                hpart[(s0 + px) * PD_ + t] = part[px][0][t] + part[px][1][t];
        } else if (t < PD_ + AD_) {
            int j = t - PD_;
            float bj = ba1[j];
#pragma unroll
            for (int px = 0; px < 4; px++) {
                float a = aprt[px][0][j] + aprt[px][1][j] + bj;
                avw[(s0 + px) * AD_ + j] = a > 0.0f ? a : 0.0f;
            }
        }
    } else {
        // ---------------- BN stats ----------------
        float (*redS)[PD_] = (float (*)[PD_])smem;
        float (*redQ)[PD_] = (float (*)[PD_])(smem + 4 * PD_);
        int tile = blk - 256;
        int b = tile >> 6;
        int hw0 = (tile & 63) << 6;
        int wave = t >> 6, lane = t & 63;
        int qd = lane >> 4, ln16 = lane & 15;

        const float* pk = feats + (size_t)b * C_ * HW_ + (hw0 + wave * 16 + ln16)
                        + (size_t)qd * 8 * HW_;
        const short8* bp = Bpk + qd * 128 + ln16;

        floatx4 acc[8];
#pragma unroll
        for (int nt = 0; nt < 8; nt++) acc[nt] = (floatx4)0.0f;

        for (int kc = 0; kc < NKC_; kc++) {
            float av[8];
#pragma unroll
            for (int j = 0; j < 8; j++) av[j] = pk[(size_t)j * HW_];

            short8 afrag;
#pragma unroll
            for (int j = 0; j < 8; j++) afrag[j] = (short)f2bf(av[j]);

#pragma unroll
            for (int nt = 0; nt < 8; nt++) {
                short8 bfrag = bp[nt * 16];
                acc[nt] = __builtin_amdgcn_mfma_f32_16x16x32_bf16(afrag, bfrag, acc[nt], 0, 0, 0);
            }
            pk += (size_t)32 * HW_;
            bp += 512;
        }

        // epilogue: acc[nt][r] = h[pixel = qd*4+r][ch = nt*16+ln16]
#pragma unroll
        for (int nt = 0; nt < 8; nt++) {
            float sq = 0.0f, sm = 0.0f;
#pragma unroll
            for (int r = 0; r < 4; r++) {
                float v = acc[nt][r];
                sq = fmaf(v, v, sq);
                sm += v;
            }
            sq += __shfl_xor(sq, 16, 64);
            sq += __shfl_xor(sq, 32, 64);
            sm += __shfl_xor(sm, 16, 64);
            sm += __shfl_xor(sm, 32, 64);
            if (qd == 0) {
                redQ[wave][nt * 16 + ln16] = sq;
                redS[wave][nt * 16 + ln16] = sm;
            }
        }
        __syncthreads();
        if (t < PD_) {
            atomicAdd(&ssq[t],  redQ[0][t] + redQ[1][t] + redQ[2][t] + redQ[3][t]);
            atomicAdd(&hsum[t], redS[0][t] + redS[1][t] + redS[2][t] + redS[3][t]);
        }
    }
}

// ---------------- finish: BN finalize (local) + BN/ReLU + W2 + attention sigmoid -------
// 64 blocks x 16 samples. mean/invstd recomputed per block from hsum/ssq (128 FLOPs).
__global__ __launch_bounds__(256) void finish_kernel(const float* __restrict__ hsum,
                                                     const float* __restrict__ ssq,
                                                     const float* __restrict__ gamma,
                                                     const float* __restrict__ beta,
                                                     const float* __restrict__ W2t,
                                                     const float* __restrict__ b2,
                                                     const float* __restrict__ Wa2,
                                                     const float* __restrict__ ba2,
                                                     const float* __restrict__ hpart,
                                                     const float* __restrict__ avw,
                                                     float* __restrict__ projs,
                                                     float* __restrict__ tw) {
    __shared__ float rh[16][PD_];    // 8 KB
    __shared__ float mn[PD_], is[PD_], gm[PD_], bt[PD_];
    int blk = blockIdx.x, t = threadIdx.x;
    int s0 = blk * 16;
    if (t < PD_) {
        float m0 = hsum[t] * (1.0f / NPIX_);
        float var = ssq[t] * (1.0f / NPIX_) - m0 * m0;
        mn[t] = m0;
        is[t] = rsqrtf(var + BN_EPS_);
        gm[t] = gamma[t];
        bt[t] = beta[t];
    }
    __syncthreads();
    for (int e = t; e < 16 * PD_; e += 256) {
        int i = e >> 7, o = e & 127;
        float h = hpart[(s0 + i) * PD_ + o];
        float r = (h - mn[o]) * is[o] * gm[o] + bt[o];
        rh[i][o] = r > 0.0f ? r : 0.0f;
    }
    __syncthreads();
    {
        int o = t & 127, grp = t >> 7;   // grp: samples grp*8 .. grp*8+7
        float p[8];
#pragma unroll
        for (int i8 = 0; i8 < 8; i8++) p[i8] = b2[o];
        for (int j = 0; j < PD_; j++) {
            float w = W2t[j * PD_ + o];
#pragma unroll
            for (int i8 = 0; i8 < 8; i8++) p[i8] = fmaf(w, rh[grp * 8 + i8][j], p[i8]);
        }
#pragma unroll
        for (int i8 = 0; i8 < 8; i8++) projs[(s0 + grp * 8 + i8) * PD_ + o] = p[i8];
    }
    if (t < 16) {
        float a2 = ba2[0];
        const float* avp = avw + (s0 + t) * AD_;
        for (int j = 0; j < AD_; j++) a2 = fmaf(Wa2[j], avp[j], a2);
        tw[s0 + t] = 1.0f / (1.0f + expf(-a2));
    }
}

// ---------------- per-image contrastive loss ----------------
__global__ __launch_bounds__(256) void loss_kernel(const float* __restrict__ projs,
                                                   const float* __restrict__ tw,
                                                   float* __restrict__ out) {
    __shared__ float f[S_][PD_ + 1];   // padded
    __shared__ float w[S_], inv[S_], rowsum[S_];
    __shared__ float sims[S_ * S_];    // 16 KB
    __shared__ float red[4];
    int b = blockIdx.x, t = threadIdx.x;
    for (int e = t; e < S_ * PD_; e += 256) {
        int i = e >> 7, c = e & 127;
        f[i][c] = projs[(b * S_ + i) * PD_ + c];
    }
    if (t < S_) w[t] = tw[b * S_ + t];
    __syncthreads();
    if (t < S_) {
        float s2 = 0.0f;
        for (int c = 0; c < PD_; c++) { float v = f[t][c]; s2 = fmaf(v, v, s2); }
        float n = sqrtf(s2);
        n = n < 1e-12f ? 1e-12f : n;
        inv[t] = 1.0f / n;
    }
    __syncthreads();
    for (int e = t; e < S_ * PD_; e += 256) {
        int i = e >> 7, c = e & 127;
        f[i][c] *= inv[i];
    }
    __syncthreads();
#pragma unroll
    for (int r = 0; r < 16; r++) {
        int e = t + 256 * r;
        int i = e >> 6, j = e & 63;
        float d = 0.0f;
        for (int c = 0; c < PD_; c++) d = fmaf(f[i][c], f[j][c], d);
        sims[e] = d * (1.0f / TEMP_);
    }
    __syncthreads();
    if (t < S_) {
        float rs = 0.0f;
        for (int jj = 0; jj < S_; jj++) {
            int j = (jj + t) & 63;
            rs += expf(sims[t * S_ + j]);
        }
        rowsum[t] = rs;
    }
    __syncthreads();
    float acc = 0.0f;
#pragma unroll
    for (int r = 0; r < 16; r++) {
        int e = t + 256 * r;
        int i = e >> 6, j = e & 63;
        float sv = sims[e];
        if (sv > THR_ && i != j) {
            float lp = logf(expf(sv) / rowsum[i] + 1e-10f);
            acc += w[i] * w[j] * lp;
        }
    }
    for (int o = 32; o > 0; o >>= 1) acc += __shfl_down(acc, o, 64);
    if ((t & 63) == 0) red[t >> 6] = acc;
    __syncthreads();
    if (t == 0) {
        float total = red[0] + red[1] + red[2] + red[3];
        float twsum = 0.0f;
        for (int i = 0; i < S_; i++) twsum += w[i];
        float loss = -(TEMP_ / BTEMP_) * total / twsum;
        atomicAdd(out, loss * (LW_ / B_));
    }
}

extern "C" void kernel_launch(void* const* d_in, const int* in_sizes, int n_in,
                              void* d_out, int out_size, void* d_ws, size_t ws_size,
                              hipStream_t stream) {
    const float* feats = (const float*)d_in[0];
    const int*   labels = (const int*)d_in[1];
    const float* W1 = (const float*)d_in[2];
    const float* b1 = (const float*)d_in[3];   (void)b1;  // cancels in BN exactly
    const float* gamma = (const float*)d_in[4];
    const float* beta = (const float*)d_in[5];
    const float* W2 = (const float*)d_in[6];
    const float* b2 = (const float*)d_in[7];
    const float* Wa1 = (const float*)d_in[8];
    const float* ba1 = (const float*)d_in[9];
    const float* Wa2 = (const float*)d_in[10];
    const float* ba2 = (const float*)d_in[11];
    float* out = (float*)d_out;

    // workspace layout — Bpk first for 16B alignment
    uint4* Bpk   = (uint4*)d_ws;                    // 32768 uint4 = 512 KB
    float* W2t   = (float*)(Bpk + NKC_ * 4 * PD_);  // 16384
    float* hsum  = W2t + PD_ * PD_;                 // 128
    float* ssq   = hsum + PD_;                      // 128
    float* tw    = ssq + PD_;                       // 1024
    int*   idx   = (int*)(tw + B_ * S_);            // 1024 ints
    float* hpart = (float*)(idx + B_ * S_);         // 131072
    float* avw   = hpart + B_ * S_ * PD_;           // 65536
    float* projs = avw + B_ * S_ * AD_;             // 131072

    prep_kernel<<<144, 256, 0, stream>>>(W1, W2, labels, W2t, Bpk, hsum, ssq, out, idx);
    mega_kernel<<<1280, 256, 0, stream>>>(feats, (const short8*)Bpk, W1, Wa1, ba1, idx,
                                          hsum, ssq, hpart, avw);
    finish_kernel<<<64, 256, 0, stream>>>(hsum, ssq, gamma, beta, W2t, b2, Wa2, ba2,
                                          hpart, avw, projs, tw);
    loss_kernel<<<B_, 256, 0, stream>>>(projs, tw, out);
}

// Round 4
// 885.711 us; speedup vs baseline: 1.1262x; 1.0109x over previous
//
#include <hip/hip_runtime.h>
#include <hip/hip_bf16.h>
#include <math.h>

#define B_ 16
#define C_ 2048
#define HW_ 4096
#define NPIX_ 65536
#define PD_ 128
#define AD_ 64
#define S_ 64
#define BN_EPS_ 1e-5f
#define TEMP_ 0.1f
#define BTEMP_ 0.07f
#define THR_ 0.7f
#define LW_ 0.1f
#define NKC_ 64   // 2048 / 32

typedef __attribute__((ext_vector_type(8))) short short8;
typedef __attribute__((ext_vector_type(4))) float floatx4;

__device__ __forceinline__ unsigned short f2bf(float x) {
    unsigned int u = __float_as_uint(x);
    u += 0x7fffu + ((u >> 16) & 1u);   // round-to-nearest-even
    return (unsigned short)(u >> 16);
}

// ---------------- prep: zero stats/out + pack W1 into bf16 MFMA B-fragment order ----------
// Bpk unit u = ((kc*4 + q)*128 + c): 8 bf16 = W1[c][kc*32+q*8 .. +7]  (16B per unit)
__global__ __launch_bounds__(256) void prep_kernel(const float* __restrict__ W1,
                                                   uint4* __restrict__ Bpk,
                                                   float* __restrict__ hsum,
                                                   float* __restrict__ ssq,
                                                   float* __restrict__ out) {
    int blk = blockIdx.x, t = threadIdx.x;
    int g = blk * 256 + t;              // g < 32768 exactly
    if (blk == 0) {
        if (t < PD_) { hsum[t] = 0.0f; ssq[t] = 0.0f; }
        if (t == 0) out[0] = 0.0f;
    }
    int kc = g >> 9, q = (g >> 7) & 3, c = g & 127;
    const float* src = W1 + (size_t)c * C_ + kc * 32 + q * 8;
    unsigned int w[4];
#pragma unroll
    for (int h = 0; h < 4; h++) {
        unsigned int lo = f2bf(src[2 * h]);
        unsigned int hi = f2bf(src[2 * h + 1]);
        w[h] = lo | (hi << 16);
    }
    Bpk[g] = make_uint4(w[0], w[1], w[2], w[3]);
}

// ---------------- mega: sample phase1 (blocks 0..255) + BN stats (blocks 256..1279) ----
// sample path: inline find (ranks s0&63 .. +3 of first valid pixels), gather 4 pixels'
//              features, compute fp32 W1.x (raw partial h) and relu(Wa1.x + ba1).
// stats path:  hsum[c]=sum_p (W1.x_p)[c], ssq[c]=sum_p (..)^2 via bf16 MFMA, atomicAdd.
// Sample blocks first: latency-bound work overlaps the BW-bound stats stream.
#define SMEM_F_ (4 * C_ + 4 * 2 * PD_ + 4 * 2 * AD_)   // 9728 floats = 38.9 KB
__global__ __launch_bounds__(256, 4) void mega_kernel(const float* __restrict__ feats,
                                                      const short8* __restrict__ Bpk,
                                                      const float* __restrict__ W1,
                                                      const float* __restrict__ Wa1,
                                                      const float* __restrict__ ba1,
                                                      const int* __restrict__ labels,
                                                      float* __restrict__ hsum,
                                                      float* __restrict__ ssq,
                                                      float* __restrict__ hpart,
                                                      float* __restrict__ avw) {
    __shared__ float smem[SMEM_F_];
    int blk = blockIdx.x, t = threadIdx.x;

    if (blk < 256) {
        // ---------------- sample phase1 ----------------
        __shared__ int pix4[4];
        int s0 = blk * 4;
        int b = s0 >> 6;               // 4 samples always within one image
        int r0 = s0 & 63;              // rank window [r0, r0+4)
        // inline find: Hillis-Steele scan of per-thread valid counts (16 labels each)
        {
            int* icnt = (int*)smem;
            const int* lb = labels + b * HW_;
            int base = t * 16, c0 = 0;
            for (int i = 0; i < 16; i++) c0 += (lb[base + i] == 1);
            icnt[t] = c0;
            if (t < 4) pix4[t] = 0;    // fill_value=0
            __syncthreads();
            for (int off = 1; off < 256; off <<= 1) {
                int v = icnt[t];
                int u = (t >= off) ? icnt[t - off] : 0;
                __syncthreads();
                icnt[t] = v + u;
                __syncthreads();
            }
            int r = icnt[t] - c0;      // exclusive prefix = global rank of my first valid
            if (r < r0 + 4 && r + c0 > r0) {
                for (int i = 0; i < 16; i++) {
                    if (lb[base + i] == 1) {
                        if (r >= r0 && r < r0 + 4) pix4[r - r0] = base + i;
                        r++;
                    }
                }
            }
            __syncthreads();
        }
        float (*x)[C_] = (float (*)[C_])smem;                              // 4x2048
        float (*part)[2][PD_] = (float (*)[2][PD_])(smem + 4 * C_);        // 4x2x128
        float (*aprt)[2][AD_] = (float (*)[2][AD_])(smem + 4 * C_ + 4 * 2 * PD_);
        const float* fb = feats + (size_t)b * C_ * HW_;
        {
            int px = t & 3;
            int pixv = pix4[px];
            for (int c = (t >> 2); c < C_; c += 64)
                x[px][c] = fb[(size_t)c * HW_ + pixv];
        }
        __syncthreads();
        // phase1a: proj first layer. o = t&127, half = t>>7, 1024 k each, 4 px
        {
            int o = t & 127, half = t >> 7;
            const float* wr = W1 + (size_t)o * C_ + half * 1024;
            float pa[4], pb[4];
#pragma unroll
            for (int px = 0; px < 4; px++) { pa[px] = 0.0f; pb[px] = 0.0f; }
            for (int k = 0; k < 1024; k += 4) {
                float4 w4 = *(const float4*)(wr + k);
#pragma unroll
                for (int px = 0; px < 4; px++) {
                    float4 x4 = *(const float4*)(&x[px][half * 1024 + k]);
                    pa[px] = fmaf(w4.x, x4.x, pa[px]);
                    pb[px] = fmaf(w4.y, x4.y, pb[px]);
                    pa[px] = fmaf(w4.z, x4.z, pa[px]);
                    pb[px] = fmaf(w4.w, x4.w, pb[px]);
                }
            }
#pragma unroll
            for (int px = 0; px < 4; px++) part[px][half][o] = pa[px] + pb[px];
        }
        // phase1b: attention first layer. threads 0..127: j = t&63, half = t>>6
        if (t < 128) {
            int j = t & 63, half = t >> 6;
            const float* wr = Wa1 + (size_t)j * C_ + half * 1024;
            float pa[4], pb[4];
#pragma unroll
            for (int px = 0; px < 4; px++) { pa[px] = 0.0f; pb[px] = 0.0f; }
            for (int k = 0; k < 1024; k += 4) {
                float4 w4 = *(const float4*)(wr + k);
#pragma unroll
                for (int px = 0; px < 4; px++) {
                    float4 x4 = *(const float4*)(&x[px][half * 1024 + k]);
                    pa[px] = fmaf(w4.x, x4.x, pa[px]);
                    pb[px] = fmaf(w4.y, x4.y, pb[px]);
                    pa[px] = fmaf(w4.z, x4.z, pa[px]);
                    pb[px] = fmaf(w4.w, x4.w, pb[px]);
                }
            }
#pragma unroll
            for (int px = 0; px < 4; px++) aprt[px][half][j] = pa[px] + pb[px];
        }
        __syncthreads();
        if (t < PD_) {
#pragma unroll
            for (int px = 0; px < 4; px++)
                hpart[(s0 + px) * PD_ + t] = part[px][0][t] + part[px][1][t];
        } else if (t < PD_ + AD_) {
            int j = t - PD_;
            float bj = ba1[j];
#pragma unroll
            for (int px = 0; px < 4; px++) {
                float a = aprt[px][0][j] + aprt[px][1][j] + bj;
                avw[(s0 + px) * AD_ + j] = a > 0.0f ? a : 0.0f;
            }
        }
    } else {
        // ---------------- BN stats ----------------
        float (*redS)[PD_] = (float (*)[PD_])smem;
        float (*redQ)[PD_] = (float (*)[PD_])(smem + 4 * PD_);
        int tile = blk - 256;
        int b = tile >> 6;
        int hw0 = (tile & 63) << 6;
        int wave = t >> 6, lane = t & 63;
        int qd = lane >> 4, ln16 = lane & 15;

        const float* pk = feats + (size_t)b * C_ * HW_ + (hw0 + wave * 16 + ln16)
                        + (size_t)qd * 8 * HW_;
        const short8* bp = Bpk + qd * 128 + ln16;

        floatx4 acc[8];
#pragma unroll
        for (int nt = 0; nt < 8; nt++) acc[nt] = (floatx4)0.0f;

        for (int kc = 0; kc < NKC_; kc++) {
            float av[8];
#pragma unroll
            for (int j = 0; j < 8; j++) av[j] = pk[(size_t)j * HW_];

            short8 afrag;
#pragma unroll
            for (int j = 0; j < 8; j++) afrag[j] = (short)f2bf(av[j]);

#pragma unroll
            for (int nt = 0; nt < 8; nt++) {
                short8 bfrag = bp[nt * 16];
                acc[nt] = __builtin_amdgcn_mfma_f32_16x16x32_bf16(afrag, bfrag, acc[nt], 0, 0, 0);
            }
            pk += (size_t)32 * HW_;
            bp += 512;
        }

        // epilogue: acc[nt][r] = h[pixel = qd*4+r][ch = nt*16+ln16]
#pragma unroll
        for (int nt = 0; nt < 8; nt++) {
            float sq = 0.0f, sm = 0.0f;
#pragma unroll
            for (int r = 0; r < 4; r++) {
                float v = acc[nt][r];
                sq = fmaf(v, v, sq);
                sm += v;
            }
            sq += __shfl_xor(sq, 16, 64);
            sq += __shfl_xor(sq, 32, 64);
            sm += __shfl_xor(sm, 16, 64);
            sm += __shfl_xor(sm, 32, 64);
            if (qd == 0) {
                redQ[wave][nt * 16 + ln16] = sq;
                redS[wave][nt * 16 + ln16] = sm;
            }
        }
        __syncthreads();
        if (t < PD_) {
            atomicAdd(&ssq[t],  redQ[0][t] + redQ[1][t] + redQ[2][t] + redQ[3][t]);
            atomicAdd(&hsum[t], redS[0][t] + redS[1][t] + redS[2][t] + redS[3][t]);
        }
    }
}

// ---------------- finish: BN finalize (local) + BN/ReLU + W2 + attention sigmoid -------
// 64 blocks x 16 samples. mean/invstd recomputed per block from hsum/ssq (128 FLOPs).
// W2 read directly (row-major, per-lane float4 row loads — L1-resident, no transpose).
__global__ __launch_bounds__(256) void finish_kernel(const float* __restrict__ hsum,
                                                     const float* __restrict__ ssq,
                                                     const float* __restrict__ gamma,
                                                     const float* __restrict__ beta,
                                                     const float* __restrict__ W2,
                                                     const float* __restrict__ b2,
                                                     const float* __restrict__ Wa2,
                                                     const float* __restrict__ ba2,
                                                     const float* __restrict__ hpart,
                                                     const float* __restrict__ avw,
                                                     float* __restrict__ projs,
                                                     float* __restrict__ tw) {
    __shared__ float rh[16][PD_];    // 8 KB, rows 512B-aligned (float4-clean)
    __shared__ float mn[PD_], is[PD_], gm[PD_], bt[PD_];
    int blk = blockIdx.x, t = threadIdx.x;
    int s0 = blk * 16;
    if (t < PD_) {
        float m0 = hsum[t] * (1.0f / NPIX_);
        float var = ssq[t] * (1.0f / NPIX_) - m0 * m0;
        mn[t] = m0;
        is[t] = rsqrtf(var + BN_EPS_);
        gm[t] = gamma[t];
        bt[t] = beta[t];
    }
    __syncthreads();
    for (int e = t; e < 16 * PD_; e += 256) {
        int i = e >> 7, o = e & 127;
        float h = hpart[(s0 + i) * PD_ + o];
        float r = (h - mn[o]) * is[o] * gm[o] + bt[o];
        rh[i][o] = r > 0.0f ? r : 0.0f;
    }
    __syncthreads();
    {
        int o = t & 127, grp = t >> 7;   // grp: samples grp*8 .. grp*8+7
        const float* wrow = W2 + (size_t)o * PD_;
        float p[8];
#pragma unroll
        for (int i8 = 0; i8 < 8; i8++) p[i8] = b2[o];
        for (int j = 0; j < PD_; j += 4) {
            float4 w4 = *(const float4*)(wrow + j);
#pragma unroll
            for (int i8 = 0; i8 < 8; i8++) {
                float4 r4 = *(const float4*)(&rh[grp * 8 + i8][j]);
                p[i8] = fmaf(w4.x, r4.x, p[i8]);
                p[i8] = fmaf(w4.y, r4.y, p[i8]);
                p[i8] = fmaf(w4.z, r4.z, p[i8]);
                p[i8] = fmaf(w4.w, r4.w, p[i8]);
            }
        }
#pragma unroll
        for (int i8 = 0; i8 < 8; i8++) projs[(s0 + grp * 8 + i8) * PD_ + o] = p[i8];
    }
    if (t < 16) {
        float a2 = ba2[0];
        const float* avp = avw + (s0 + t) * AD_;
        for (int j = 0; j < AD_; j++) a2 = fmaf(Wa2[j], avp[j], a2);
        tw[s0 + t] = 1.0f / (1.0f + expf(-a2));
    }
}

// ---------------- per-image contrastive loss ----------------
__global__ __launch_bounds__(256) void loss_kernel(const float* __restrict__ projs,
                                                   const float* __restrict__ tw,
                                                   float* __restrict__ out) {
    __shared__ float f[S_][PD_ + 1];   // padded
    __shared__ float w[S_], inv[S_], rowsum[S_];
    __shared__ float sims[S_ * S_];    // 16 KB
    __shared__ float red[4];
    int b = blockIdx.x, t = threadIdx.x;
    for (int e = t; e < S_ * PD_; e += 256) {
        int i = e >> 7, c = e & 127;
        f[i][c] = projs[(b * S_ + i) * PD_ + c];
    }
    if (t < S_) w[t] = tw[b * S_ + t];
    __syncthreads();
    if (t < S_) {
        float s2 = 0.0f;
        for (int c = 0; c < PD_; c++) { float v = f[t][c]; s2 = fmaf(v, v, s2); }
        float n = sqrtf(s2);
        n = n < 1e-12f ? 1e-12f : n;
        inv[t] = 1.0f / n;
    }
    __syncthreads();
    for (int e = t; e < S_ * PD_; e += 256) {
        int i = e >> 7, c = e & 127;
        f[i][c] *= inv[i];
    }
    __syncthreads();
#pragma unroll
    for (int r = 0; r < 16; r++) {
        int e = t + 256 * r;
        int i = e >> 6, j = e & 63;
        float d = 0.0f;
        for (int c = 0; c < PD_; c++) d = fmaf(f[i][c], f[j][c], d);
        sims[e] = d * (1.0f / TEMP_);
    }
    __syncthreads();
    if (t < S_) {
        float rs = 0.0f;
        for (int jj = 0; jj < S_; jj++) {
            int j = (jj + t) & 63;
            rs += expf(sims[t * S_ + j]);
        }
        rowsum[t] = rs;
    }
    __syncthreads();
    float acc = 0.0f;
#pragma unroll
    for (int r = 0; r < 16; r++) {
        int e = t + 256 * r;
        int i = e >> 6, j = e & 63;
        float sv = sims[e];
        if (sv > THR_ && i != j) {
            float lp = logf(expf(sv) / rowsum[i] + 1e-10f);
            acc += w[i] * w[j] * lp;
        }
    }
    for (int o = 32; o > 0; o >>= 1) acc += __shfl_down(acc, o, 64);
    if ((t & 63) == 0) red[t >> 6] = acc;
    __syncthreads();
    if (t == 0) {
        float total = red[0] + red[1] + red[2] + red[3];
        float twsum = 0.0f;
        for (int i = 0; i < S_; i++) twsum += w[i];
        float loss = -(TEMP_ / BTEMP_) * total / twsum;
        atomicAdd(out, loss * (LW_ / B_));
    }
}

extern "C" void kernel_launch(void* const* d_in, const int* in_sizes, int n_in,
                              void* d_out, int out_size, void* d_ws, size_t ws_size,
                              hipStream_t stream) {
    const float* feats = (const float*)d_in[0];
    const int*   labels = (const int*)d_in[1];
    const float* W1 = (const float*)d_in[2];
    const float* b1 = (const float*)d_in[3];   (void)b1;  // cancels in BN exactly
    const float* gamma = (const float*)d_in[4];
    const float* beta = (const float*)d_in[5];
    const float* W2 = (const float*)d_in[6];
    const float* b2 = (const float*)d_in[7];
    const float* Wa1 = (const float*)d_in[8];
    const float* ba1 = (const float*)d_in[9];
    const float* Wa2 = (const float*)d_in[10];
    const float* ba2 = (const float*)d_in[11];
    float* out = (float*)d_out;

    // workspace layout — Bpk first for 16B alignment
    uint4* Bpk   = (uint4*)d_ws;                    // 32768 uint4 = 512 KB
    float* hsum  = (float*)(Bpk + NKC_ * 4 * PD_);  // 128
    float* ssq   = hsum + PD_;                      // 128
    float* tw    = ssq + PD_;                       // 1024
    float* hpart = tw + B_ * S_;                    // 131072
    float* avw   = hpart + B_ * S_ * PD_;           // 65536
    float* projs = avw + B_ * S_ * AD_;             // 131072

    prep_kernel<<<128, 256, 0, stream>>>(W1, Bpk, hsum, ssq, out);
    mega_kernel<<<1280, 256, 0, stream>>>(feats, (const short8*)Bpk, W1, Wa1, ba1,
                                          labels, hsum, ssq, hpart, avw);
    finish_kernel<<<64, 256, 0, stream>>>(hsum, ssq, gamma, beta, W2, b2, Wa2, ba2,
                                          hpart, avw, projs, tw);
    loss_kernel<<<B_, 256, 0, stream>>>(projs, tw, out);
}